// Round 1
// baseline (7527.460 us; speedup 1.0000x reference)
//
#include <hip/hip_runtime.h>

#define NWG     256
#define TPB     256
#define NL0     128          // WGs [0,128) = layer0, [128,256) = layer1
#define T_STEPS 1024
#define HD      1024
#define DIN     256
#define K0      1280         // DIN + HD
#define K1      2048         // HD + HD
#define K0P     1288         // padded LDS row stride (shorts)
#define K1P     2056
#define REDSZ   8192         // cross-wave K-reduction scratch (4 waves x 2 rg x 64 lanes x 16B)
#define SMEM_BYTES (32*K1P*2 + REDSZ)   // 139,776 B

#define HSLAB_BYTES 131072ull            // one h snapshot: 128 planes x 64 batch x 8 bf16
#define HSLAB_U64   16384
#define HIST_DEPTH  1025                 // slot(t)=(t+1)%1025 never wraps in 1024 steps
#define HIST_BYTES  (HIST_DEPTH*HSLAB_BYTES)   // 134,348,800
#define X8_BYTES    33554432ull
#define FLAGS_BYTES 32768ull

typedef float  f32x4  __attribute__((ext_vector_type(4)));
typedef __bf16 bf16x8 __attribute__((ext_vector_type(8)));
typedef int    i32x4  __attribute__((ext_vector_type(4)));
typedef unsigned long long u64;

__device__ __forceinline__ unsigned short f2bf(float f){
  union { float f; unsigned u; } a; a.f = f;
  unsigned u = a.u;
  u += 0x7fffu + ((u >> 16) & 1u);   // RNE
  return (unsigned short)(u >> 16);
}
__device__ __forceinline__ float sigmf(float x){ return 1.0f/(1.0f + __expf(-x)); }
__device__ __forceinline__ float tanhf_fast(float x){ return 2.0f*sigmf(2.0f*x) - 1.0f; }

// coherent (MALL-level, cross-XCD) accessors — per-access, no L2 invalidation
__device__ __forceinline__ u64 ld64c(const u64* p){
  return __hip_atomic_load(p, __ATOMIC_RELAXED, __HIP_MEMORY_SCOPE_AGENT);
}
__device__ __forceinline__ unsigned ldflag(const unsigned* p){
  return __hip_atomic_load(p, __ATOMIC_RELAXED, __HIP_MEMORY_SCOPE_AGENT);
}
__device__ __forceinline__ void stflag(unsigned* p, unsigned v){
  __hip_atomic_store(p, v, __ATOMIC_RELAXED, __HIP_MEMORY_SCOPE_AGENT);
}
// 16B coherent write-through store (full-line-friendly; replaces 8 scattered u16 stores)
__device__ __forceinline__ void st128c(void* p, i32x4 v){
  asm volatile("global_store_dwordx4 %0, %1, off sc0 sc1" :: "v"(p), "v"(v) : "memory");
}
__device__ __forceinline__ i32x4 ld128(const void* p, bool coh){
  if (coh){
    u64 a = ld64c((const u64*)p);
    u64 b = ld64c(((const u64*)p) + 1);
    i32x4 r;
    __builtin_memcpy(&r, &a, 8);
    __builtin_memcpy(((char*)&r) + 8, &b, 8);
    return r;
  }
  i32x4 r;
  __builtin_memcpy(&r, p, 16);
  return r;
}

// one-hop all-to-all barrier: WG i stores flags[i]; thread tid polls WG tid's
// flag. npoll selects how many WGs to join with (layer0 in deep-history tiers
// only joins its own 128 — ring depth 1025 makes running ahead safe).
__device__ __forceinline__ void gridbar(unsigned* flags, unsigned ep, int wg, int tid, int npoll){
  asm volatile("s_waitcnt vmcnt(0)" ::: "memory");  // sc1 h-stores at MALL
  __syncthreads();                                  // whole WG drained
  if (tid == 0) stflag(&flags[wg*16], ep);
  if (tid < npoll)
    while (ldflag(&flags[tid*16]) < ep) __builtin_amdgcn_s_sleep(1);
  __syncthreads();                                  // all polled flags confirmed
}

// x [B,T,D] fp32 -> X8 bf16 in [T][D/8][B][8]
__global__ void xpose_kernel(const float* __restrict__ x, unsigned short* __restrict__ X8){
  int idx   = blockIdx.x*256 + threadIdx.x;
  int t     = idx >> 11;
  int rem   = idx & 2047;
  int plane = rem >> 6;
  int b     = rem & 63;
  const float* src = x + ((size_t)b << 18) + (t << 8) + (plane << 3);
  unsigned short tmp[8];
  #pragma unroll
  for (int j = 0; j < 8; ++j) tmp[j] = f2bf(src[j]);
  int4 v; __builtin_memcpy(&v, tmp, 16);
  ((int4*)X8)[idx] = v;
}

// Wave decomposition (new): wave wv -> bh = wv>>1 (batch half: 32 batches),
// kh = wv&1 (K half). Each wave reads each A-fragment ONCE and feeds 4 MFMAs
// (2 row-groups x 2 batch-groups) -> LDS weight traffic halved vs 4-way batch
// split. Pairwise K-reduction through LDS; finalized batch = wv*16+nn (same
// thread->state mapping as before, epilogue/out unchanged).
template<bool H0C, bool H1C>
__global__ void __launch_bounds__(TPB, 1)
lstm_mega(const float* __restrict__ Wih0, const float* __restrict__ Whh0,
          const float* __restrict__ bih0, const float* __restrict__ bhh0,
          const float* __restrict__ Wih1, const float* __restrict__ Whh1,
          const float* __restrict__ bih1, const float* __restrict__ bhh1,
          const unsigned short* __restrict__ X8,
          unsigned* flags, unsigned* gen,
          u64* H0, u64* H1, int d0, int d1,
          float* __restrict__ out)
{
  extern __shared__ unsigned short Ws[];   // [32][KP] + Red scratch
  const int tid   = threadIdx.x;
  const int wg    = blockIdx.x;
  const int layer = (wg >= NL0);
  const int wgl   = layer ? wg - NL0 : wg;
  const int KD    = layer ? K1  : K0;
  const int dlen  = layer ? HD  : DIN;
  const int KP    = layer ? K1P : K0P;
  const char* X8b = (const char*)X8;

  // ---- stage this WG's 32 gate-rows (8 cols x 4 gates) into LDS (bf16) ----
  {
    const float* Wih = layer ? Wih1 : Wih0;
    const float* Whh = layer ? Whh1 : Whh0;
    for (int m = 0; m < 32; ++m){
      int gr = (m & 3)*HD + wgl*8 + (m >> 2);      // gate-major global row
      const float* ar = Wih + (size_t)gr*dlen;
      const float* br = Whh + (size_t)gr*HD;
      unsigned short* row = Ws + m*KP;
      for (int k = tid; k < KD; k += TPB)
        row[k] = f2bf(k < dlen ? ar[k] : br[k - dlen]);
    }
  }
  __syncthreads();

  const int lane  = tid & 63;
  const int wv    = tid >> 6;
  const int q     = lane >> 4;       // k-quad (A/B frags); row-quad (C/D)
  const int nn    = lane & 15;       // A-row / B-batch / C-batch
  const int bh    = wv >> 1;         // batch half (0..1)
  const int kh    = wv & 1;          // K half (0..1)
  const int batA  = bh*32 + nn;        // batch-group 0 of this wave
  const int batB  = bh*32 + 16 + nn;   // batch-group 1 of this wave

  f32x4* Red = (f32x4*)(Ws + 32*KP);   // [wv][rg][lane] f32x4 scratch

  float bias[2][4];
  {
    const float* bi  = layer ? bih1 : bih0;
    const float* bhp = layer ? bhh1 : bhh0;
    #pragma unroll
    for (int rt = 0; rt < 2; ++rt){
      int colr = wgl*8 + rt*4 + q;
      #pragma unroll
      for (int r = 0; r < 4; ++r)
        bias[rt][r] = bi[r*HD + colr] + bhp[r*HD + colr];
    }
  }

  float cst[2] = {0.f, 0.f};
  float hv[2]  = {0.f, 0.f};

  // pairwise K-reduction (wv ^ 1 holds the other K half) + gates + packed store
  auto epilogue = [&](f32x4 a00, f32x4 a01, f32x4 a10, f32x4 a11,
                      u64* Hw, int wd, int t){
    // send the batch-group the partner finalizes; keep bgl == kh
    Red[(wv*2+0)*64 + lane] = kh ? a00 : a01;
    Red[(wv*2+1)*64 + lane] = kh ? a10 : a11;
    __syncthreads();
    const int pw = wv ^ 1;
    f32x4 s0 = (kh ? a01 : a00) + Red[(pw*2+0)*64 + lane];
    f32x4 s1 = (kh ? a11 : a10) + Red[(pw*2+1)*64 + lane];
    #pragma unroll
    for (int rt = 0; rt < 2; ++rt){
      f32x4 s = rt ? s1 : s0;
      float ii = sigmf(s[0] + bias[rt][0]);
      float ff = sigmf(s[1] + bias[rt][1]);
      float gg = tanhf_fast(s[2] + bias[rt][2]);
      float oo = sigmf(s[3] + bias[rt][3]);
      cst[rt] = ff*cst[rt] + ii*gg;
      hv[rt]  = oo*tanhf_fast(cst[rt]);
    }
    // pack 8 bf16 of one batch into one lane -> single 16B coherent store
    unsigned hpk = ((unsigned)f2bf(hv[1]) << 16) | (unsigned)f2bf(hv[0]);
    unsigned g0 = __shfl(hpk, nn);
    unsigned g1 = __shfl(hpk, nn + 16);
    unsigned g2 = __shfl(hpk, nn + 32);
    unsigned g3 = __shfl(hpk, nn + 48);
    if (q == 0){
      i32x4 v;
      v.x = (int)((g0 & 0xffffu) | (g1 << 16));       // rt0: q0,q1
      v.y = (int)((g2 & 0xffffu) | (g3 << 16));       // rt0: q2,q3
      v.z = (int)((g0 >> 16) | (g1 & 0xffff0000u));   // rt1: q0,q1
      v.w = (int)((g2 >> 16) | (g3 & 0xffff0000u));   // rt1: q2,q3
      char* wbase = (char*)(Hw + (size_t)((t+1) % wd)*HSLAB_U64);
      st128c(wbase + ((wgl*64 + wv*16 + nn) << 4), v);
    }
  };

  // ---- layer 0: gates = W0 @ [x_t ; h0(t-1)], wave handles kb = kh*20+j ----
  auto step0 = [&](int t){
    const char* hb0 = (const char*)(H0 + (size_t)(t % d0)*HSLAB_U64);
    const char* xb  = X8b + ((size_t)t << 15);
    i32x4 Bf[40];                        // all 40 16B loads issued up front
    #pragma unroll
    for (int j = 0; j < 20; ++j){
      const int kb = kh*20 + j;
      if (kb < 8){                       // x part (only wave kh==0)
        const char* p = xb + (((kb*4 + q)*64) << 4);
        Bf[2*j]   = ld128(p + (batA << 4), false);
        Bf[2*j+1] = ld128(p + (batB << 4), false);
      } else {                           // h0(t-1)
        const char* p = hb0 + ((((kb-8)*4 + q)*64) << 4);
        Bf[2*j]   = ld128(p + (batA << 4), H0C);
        Bf[2*j+1] = ld128(p + (batB << 4), H0C);
      }
    }
    f32x4 a00 = {0,0,0,0}, a01 = {0,0,0,0}, a10 = {0,0,0,0}, a11 = {0,0,0,0};
    #pragma unroll
    for (int j = 0; j < 20; ++j){
      const int kb = kh*20 + j;
      bf16x8 a0, a1, v0, v1;
      __builtin_memcpy(&a0, &Ws[nn*KP + kb*32 + q*8], 16);
      __builtin_memcpy(&a1, &Ws[(16+nn)*KP + kb*32 + q*8], 16);
      __builtin_memcpy(&v0, &Bf[2*j], 16);
      __builtin_memcpy(&v1, &Bf[2*j+1], 16);
      a00 = __builtin_amdgcn_mfma_f32_16x16x32_bf16(a0, v0, a00, 0, 0, 0);
      a01 = __builtin_amdgcn_mfma_f32_16x16x32_bf16(a0, v1, a01, 0, 0, 0);
      a10 = __builtin_amdgcn_mfma_f32_16x16x32_bf16(a1, v0, a10, 0, 0, 0);
      a11 = __builtin_amdgcn_mfma_f32_16x16x32_bf16(a1, v1, a11, 0, 0, 0);
    }
    epilogue(a00, a01, a10, a11, H0, d0, t);
  };

  // ---- layer 1: gates = W1 @ [y0(t) ; h1(t-1)]; wave kh=0 reads only y0,
  // wave kh=1 only h1. 8 chunks of 8x16B; depth-6 ring, 48 loads in flight ----
  auto step1 = [&](int t){
    const char* yb  = (const char*)(H0 + (size_t)((t+1) % d0)*HSLAB_U64);
    const char* hb1 = (const char*)(H1 + (size_t)(t % d1)*HSLAB_U64);
    const char* src = kh ? hb1 : yb;
    const bool  coh = kh ? H1C : H0C;
    i32x4 Bf[6][8];
    auto LDC = [&](int c){               // chunk c: kb group c>>1, bgl c&1
      const int g   = c >> 1;
      const int bat = (c & 1) ? batB : batA;
      const char* p = src + (((g*32 + q)*64 + bat) << 4);
      #pragma unroll
      for (int i = 0; i < 8; ++i)
        Bf[c % 6][i] = ld128(p + i*4096, coh);
    };
    LDC(0); LDC(1); LDC(2); LDC(3); LDC(4); LDC(5);
    f32x4 a00 = {0,0,0,0}, a01 = {0,0,0,0}, a10 = {0,0,0,0}, a11 = {0,0,0,0};
    #pragma unroll
    for (int g = 0; g < 4; ++g){
      #pragma unroll
      for (int i = 0; i < 8; ++i){
        const int kb = kh*32 + g*8 + i;
        bf16x8 a0, a1, v0, v1;
        __builtin_memcpy(&a0, &Ws[nn*KP + kb*32 + q*8], 16);
        __builtin_memcpy(&a1, &Ws[(16+nn)*KP + kb*32 + q*8], 16);
        __builtin_memcpy(&v0, &Bf[(2*g) % 6][i], 16);
        __builtin_memcpy(&v1, &Bf[(2*g+1) % 6][i], 16);
        a00 = __builtin_amdgcn_mfma_f32_16x16x32_bf16(a0, v0, a00, 0, 0, 0);
        a01 = __builtin_amdgcn_mfma_f32_16x16x32_bf16(a0, v1, a01, 0, 0, 0);
        a10 = __builtin_amdgcn_mfma_f32_16x16x32_bf16(a1, v0, a10, 0, 0, 0);
        a11 = __builtin_amdgcn_mfma_f32_16x16x32_bf16(a1, v1, a11, 0, 0, 0);
      }
      if (g == 0){ LDC(6); LDC(7); }
    }
    epilogue(a00, a01, a10, a11, H1, d1, t);
  };

  if (!layer){
    // deep-history tiers: layer0 joins only its own 128 WGs and runs ahead
    // (slots never reused). tier0 (d0==2) reuses slots -> must full-join.
    const int npoll0 = (d0 >= T_STEPS + 1) ? NL0 : NWG;
    for (int s = 0; s < T_STEPS; ++s){
      step0(s);
      gridbar(flags, (unsigned)(s+1), wg, tid, npoll0);
    }
  } else {
    for (int s = 0; s < T_STEPS; ++s){
      if (s > 0) step1(s-1);
      gridbar(flags, (unsigned)(s+1), wg, tid, NWG);
    }
    step1(T_STEPS-1);
  }

  // out = [h0 | h1 | c0 | c1], each [B=64, H=1024] fp32
  {
    const int col0  = wgl*8 + q;
    const int base  = layer ? 65536 : 0;
    const int batch = wv*16 + nn;
    out[base          + batch*HD + col0    ] = hv[0];
    out[base          + batch*HD + col0 + 4] = hv[1];
    out[base + 131072 + batch*HD + col0    ] = cst[0];
    out[base + 131072 + batch*HD + col0 + 4] = cst[1];
  }
}

extern "C" void kernel_launch(void* const* d_in, const int* in_sizes, int n_in,
                              void* d_out, int out_size, void* d_ws, size_t ws_size,
                              hipStream_t stream)
{
  const float* x    = (const float*)d_in[0];
  const float* Wih0 = (const float*)d_in[1];
  const float* Whh0 = (const float*)d_in[2];
  const float* bih0 = (const float*)d_in[3];
  const float* bhh0 = (const float*)d_in[4];
  const float* Wih1 = (const float*)d_in[5];
  const float* Whh1 = (const float*)d_in[6];
  const float* bih1 = (const float*)d_in[7];
  const float* bhh1 = (const float*)d_in[8];
  float* out = (float*)d_out;

  char* ws = (char*)d_ws;
  unsigned* flags = (unsigned*)ws;
  unsigned* gen   = (unsigned*)(ws + 16384);

  const size_t need2 = FLAGS_BYTES + 2*HIST_BYTES + X8_BYTES;               // ~302 MB
  const size_t need1 = FLAGS_BYTES + HIST_BYTES + 2*HSLAB_BYTES + X8_BYTES; // ~168 MB

  u64 *H0p, *H1p; unsigned short* X8p; int d0, d1, tier;
  if (ws_size >= need2){
    tier = 2; d0 = HIST_DEPTH; d1 = HIST_DEPTH;
    H0p = (u64*)(ws + FLAGS_BYTES);
    H1p = (u64*)(ws + FLAGS_BYTES + HIST_BYTES);
    X8p = (unsigned short*)(ws + FLAGS_BYTES + 2*HIST_BYTES);
  } else if (ws_size >= need1){
    tier = 1; d0 = HIST_DEPTH; d1 = 2;
    H0p = (u64*)(ws + FLAGS_BYTES);
    H1p = (u64*)(ws + FLAGS_BYTES + HIST_BYTES);
    X8p = (unsigned short*)(ws + FLAGS_BYTES + HIST_BYTES + 2*HSLAB_BYTES);
  } else {
    tier = 0; d0 = 2; d1 = 2;
    H0p = (u64*)(ws + FLAGS_BYTES);
    H1p = (u64*)(ws + FLAGS_BYTES + 2*HSLAB_BYTES);
    X8p = (unsigned short*)(ws + FLAGS_BYTES + 4*HSLAB_BYTES);
  }

  // zero flags + slot 0 of each h buffer (initial state h(-1)=0)
  hipMemsetAsync(flags, 0, FLAGS_BYTES, stream);
  hipMemsetAsync(H0p, 0, HSLAB_BYTES, stream);
  hipMemsetAsync(H1p, 0, HSLAB_BYTES, stream);
  xpose_kernel<<<8192, 256, 0, stream>>>(x, X8p);

  void* fn = (tier == 2) ? (void*)&lstm_mega<false,false>
           : (tier == 1) ? (void*)&lstm_mega<false,true>
                         : (void*)&lstm_mega<true,true>;
  hipFuncSetAttribute(fn, hipFuncAttributeMaxDynamicSharedMemorySize, SMEM_BYTES);

  const unsigned short* X8c = X8p;
  void* args[] = {(void*)&Wih0,(void*)&Whh0,(void*)&bih0,(void*)&bhh0,
                  (void*)&Wih1,(void*)&Whh1,(void*)&bih1,(void*)&bhh1,
                  (void*)&X8c,(void*)&flags,(void*)&gen,
                  (void*)&H0p,(void*)&H1p,(void*)&d0,(void*)&d1,(void*)&out};
  hipError_t err = hipLaunchCooperativeKernel(fn, dim3(NWG), dim3(TPB),
                                              args, SMEM_BYTES, stream);
  if (err != hipSuccess){
    // Fallback: plain launch. 256 WGs x ~136KB LDS => 1 WG/CU, grid == CU
    // count, all WGs co-resident by capacity.
    if (tier == 2)
      lstm_mega<false,false><<<dim3(NWG), dim3(TPB), SMEM_BYTES, stream>>>(
        Wih0,Whh0,bih0,bhh0,Wih1,Whh1,bih1,bhh1,X8c,flags,gen,H0p,H1p,d0,d1,out);
    else if (tier == 1)
      lstm_mega<false,true><<<dim3(NWG), dim3(TPB), SMEM_BYTES, stream>>>(
        Wih0,Whh0,bih0,bhh0,Wih1,Whh1,bih1,bhh1,X8c,flags,gen,H0p,H1p,d0,d1,out);
    else
      lstm_mega<true,true><<<dim3(NWG), dim3(TPB), SMEM_BYTES, stream>>>(
        Wih0,Whh0,bih0,bhh0,Wih1,Whh1,bih1,bhh1,X8c,flags,gen,H0p,H1p,d0,d1,out);
  }
}

// Round 2
// 5933.235 us; speedup vs baseline: 1.2687x; 1.2687x over previous
//
#include <hip/hip_runtime.h>

#define NWG     256
#define TPB     256
#define NL0     128          // WGs [0,128) = layer0, [128,256) = layer1
#define T_STEPS 1024
#define HD      1024
#define DIN     256
#define K0      1280         // DIN + HD
#define K1      2048         // HD + HD
#define K0P     1288         // padded LDS row stride (shorts)
#define K1P     2056
#define SMEM_BYTES (32*K1P*2)   // 131,584 B (layer1 worst case)

#define HSLAB_BYTES 131072ull            // one h snapshot: 128 planes x 64 batch x 8 bf16
#define HSLAB_U64   16384
#define HIST_DEPTH  1025                 // slot(t)=(t+1)%1025 never wraps in 1024 steps
#define HIST_BYTES  (HIST_DEPTH*HSLAB_BYTES)   // 134,348,800
#define X8_BYTES    33554432ull
#define FLAGS_BYTES 32768ull

typedef float  f32x4  __attribute__((ext_vector_type(4)));
typedef __bf16 bf16x8 __attribute__((ext_vector_type(8)));
typedef int    i32x4  __attribute__((ext_vector_type(4)));
typedef unsigned long long u64;

__device__ __forceinline__ unsigned short f2bf(float f){
  union { float f; unsigned u; } a; a.f = f;
  unsigned u = a.u;
  u += 0x7fffu + ((u >> 16) & 1u);   // RNE
  return (unsigned short)(u >> 16);
}
__device__ __forceinline__ float sigmf(float x){ return 1.0f/(1.0f + __expf(-x)); }
__device__ __forceinline__ float tanhf_fast(float x){ return 2.0f*sigmf(2.0f*x) - 1.0f; }

// coherent (MALL-level, cross-XCD) accessors — per-access, no L2 invalidation
__device__ __forceinline__ u64 ld64c(const u64* p){
  return __hip_atomic_load(p, __ATOMIC_RELAXED, __HIP_MEMORY_SCOPE_AGENT);
}
__device__ __forceinline__ unsigned ldflag(const unsigned* p){
  return __hip_atomic_load(p, __ATOMIC_RELAXED, __HIP_MEMORY_SCOPE_AGENT);
}
__device__ __forceinline__ void stflag(unsigned* p, unsigned v){
  __hip_atomic_store(p, v, __ATOMIC_RELAXED, __HIP_MEMORY_SCOPE_AGENT);
}
// 16B coherent write-through store (full lines: faster drain, no RMW at MALL)
__device__ __forceinline__ void st128c(void* p, i32x4 v){
  asm volatile("global_store_dwordx4 %0, %1, off sc0 sc1" :: "v"(p), "v"(v) : "memory");
}

// x [B,T,D] fp32 -> X8 bf16 in [T][D/8][B][8]
__global__ void xpose_kernel(const float* __restrict__ x, unsigned short* __restrict__ X8){
  int idx   = blockIdx.x*256 + threadIdx.x;
  int t     = idx >> 11;
  int rem   = idx & 2047;
  int plane = rem >> 6;
  int b     = rem & 63;
  const float* src = x + ((size_t)b << 18) + (t << 8) + (plane << 3);
  unsigned short tmp[8];
  #pragma unroll
  for (int j = 0; j < 8; ++j) tmp[j] = f2bf(src[j]);
  int4 v; __builtin_memcpy(&v, tmp, 16);
  ((int4*)X8)[idx] = v;
}

// Decoupled schedule (deep-history tiers): layer0 joins ONLY its own 128
// flags -> shorter chain -> runs ahead. Layer1 joins layer0 flags (instant
// once layer0 is ahead; cached last-seen value skips even the poll load) and
// its own group's flags, placed AFTER the y0-half MFMAs so the h1 MALL-load
// latency hides under compute. Tier0 (slot reuse) keeps legacy full lockstep.
template<bool H0C, bool H1C>
__global__ void __launch_bounds__(TPB, 1)
lstm_mega(const float* __restrict__ Wih0, const float* __restrict__ Whh0,
          const float* __restrict__ bih0, const float* __restrict__ bhh0,
          const float* __restrict__ Wih1, const float* __restrict__ Whh1,
          const float* __restrict__ bih1, const float* __restrict__ bhh1,
          const unsigned short* __restrict__ X8,
          unsigned* flags, unsigned* gen,
          u64* H0, u64* H1, int d0, int d1,
          float* __restrict__ out)
{
  extern __shared__ unsigned short Ws[];   // [32][KP]
  const int tid   = threadIdx.x;
  const int wg    = blockIdx.x;
  const int layer = (wg >= NL0);
  const int wgl   = layer ? wg - NL0 : wg;
  const int KD    = layer ? K1  : K0;
  const int dlen  = layer ? HD  : DIN;
  const int KP    = layer ? K1P : K0P;
  const int4* X4  = (const int4*)X8;

  // ---- stage this WG's 32 gate-rows (8 cols x 4 gates) into LDS (bf16) ----
  {
    const float* Wih = layer ? Wih1 : Wih0;
    const float* Whh = layer ? Whh1 : Whh0;
    for (int m = 0; m < 32; ++m){
      int gr = (m & 3)*HD + wgl*8 + (m >> 2);      // gate-major global row
      const float* ar = Wih + (size_t)gr*dlen;
      const float* br = Whh + (size_t)gr*HD;
      unsigned short* row = Ws + m*KP;
      for (int k = tid; k < KD; k += TPB)
        row[k] = f2bf(k < dlen ? ar[k] : br[k - dlen]);
    }
  }
  __syncthreads();

  const int lane  = tid & 63;
  const int wv    = tid >> 6;
  const int q     = lane >> 4;       // k-quad (A/B frags); row-quad (C/D)
  const int nn    = lane & 15;       // A-row / B-batch / C-batch
  const int batch = wv*16 + nn;

  float bias[2][4];
  {
    const float* bi = layer ? bih1 : bih0;
    const float* bh = layer ? bhh1 : bhh0;
    #pragma unroll
    for (int rt = 0; rt < 2; ++rt){
      int colr = wgl*8 + rt*4 + q;
      #pragma unroll
      for (int r = 0; r < 4; ++r)
        bias[rt][r] = bi[r*HD + colr] + bh[r*HD + colr];
    }
  }

  float cst[2] = {0.f, 0.f};
  float hv[2]  = {0.f, 0.f};
  f32x4 a00, a01, a10, a11;

  auto MM = [&](int kb, bf16x8 b){
    bf16x8 a0, a1;
    __builtin_memcpy(&a0, &Ws[nn*KP + kb*32 + q*8], 16);
    __builtin_memcpy(&a1, &Ws[(16+nn)*KP + kb*32 + q*8], 16);
    if (kb & 1){ a01 = __builtin_amdgcn_mfma_f32_16x16x32_bf16(a0,b,a01,0,0,0);
                 a11 = __builtin_amdgcn_mfma_f32_16x16x32_bf16(a1,b,a11,0,0,0); }
    else       { a00 = __builtin_amdgcn_mfma_f32_16x16x32_bf16(a0,b,a00,0,0,0);
                 a10 = __builtin_amdgcn_mfma_f32_16x16x32_bf16(a1,b,a10,0,0,0); }
  };
  auto CHUNK = [&](int kb0, u64* d){     // consume one 8-plane chunk
    #pragma unroll
    for (int i = 0; i < 8; ++i){
      u64 pair[2] = {d[2*i], d[2*i+1]};
      bf16x8 b; __builtin_memcpy(&b, pair, 16);
      MM(kb0 + i, b);
    }
  };

  // ---- flag machinery (flags are monotonic; seen-cache skips proven polls) ----
  unsigned seenA = 0, seenB = 0;
  auto waitL0 = [&](unsigned ep){
    if (tid < NL0 && seenA < ep){
      const unsigned* p = &flags[tid*16];
      unsigned v = ldflag(p);
      while (v < ep){ __builtin_amdgcn_s_sleep(1); v = ldflag(p); }
      seenA = v;
    }
    __syncthreads();
  };
  auto waitL1 = [&](unsigned ep){
    if (tid < NL0 && seenB < ep){
      const unsigned* p = &flags[(NL0 + tid)*16];
      unsigned v = ldflag(p);
      while (v < ep){ __builtin_amdgcn_s_sleep(1); v = ldflag(p); }
      seenB = v;
    }
    __syncthreads();
  };
  auto postF = [&](unsigned ep){
    asm volatile("s_waitcnt vmcnt(0)" ::: "memory");  // sc stores at MALL
    __syncthreads();                                  // whole WG drained
    if (tid == 0) stflag(&flags[wg*16], ep);
  };
  auto waitAll = [&](unsigned ep){                    // legacy full join (tier0)
    while (ldflag(&flags[tid*16]) < ep) __builtin_amdgcn_s_sleep(1);
    __syncthreads();
  };

  u64 B0[16], B1[16], B2[16];   // depth-3 chunk ring (proven round-0 idiom)

  auto epilogue = [&](u64* Hw, int wd, int t){
    f32x4 s0 = a00 + a01, s1 = a10 + a11;
    #pragma unroll
    for (int rt = 0; rt < 2; ++rt){
      f32x4 s = rt ? s1 : s0;
      float ii = sigmf(s[0] + bias[rt][0]);
      float ff = sigmf(s[1] + bias[rt][1]);
      float gg = tanhf_fast(s[2] + bias[rt][2]);
      float oo = sigmf(s[3] + bias[rt][3]);
      cst[rt] = ff*cst[rt] + ii*gg;
      hv[rt]  = oo*tanhf_fast(cst[rt]);
    }
    // pack 8 bf16 of one batch into one lane -> single 16B coherent store
    unsigned hpk = ((unsigned)f2bf(hv[1]) << 16) | (unsigned)f2bf(hv[0]);
    unsigned g0 = __shfl(hpk, nn);
    unsigned g1 = __shfl(hpk, nn + 16);
    unsigned g2 = __shfl(hpk, nn + 32);
    unsigned g3 = __shfl(hpk, nn + 48);
    if (q == 0){
      i32x4 v;
      v.x = (int)((g0 & 0xffffu) | (g1 << 16));       // rt0: q0,q1
      v.y = (int)((g2 & 0xffffu) | (g3 << 16));       // rt0: q2,q3
      v.z = (int)((g0 >> 16) | (g1 & 0xffff0000u));   // rt1: q0,q1
      v.w = (int)((g2 >> 16) | (g3 & 0xffff0000u));   // rt1: q2,q3
      char* wbase = (char*)(Hw + (size_t)((t+1) % wd)*HSLAB_U64);
      st128c(wbase + ((wgl*64 + wv*16 + nn) << 4), v);
    }
  };

  // ---- layer 0 step: gates = W0 @ [x_t ; h0(t-1)] ----
  auto step0 = [&](int t, bool dec){
    a00 = (f32x4){0,0,0,0}; a01 = a00; a10 = a00; a11 = a00;
    const int4* xb = X4 + (size_t)t*2048;
    const u64* hb  = H0 + (size_t)(t % d0)*HSLAB_U64;     // h0(t-1) slot
    auto LDH = [&](int c, u64* d){                        // h planes c*8..c*8+7
      #pragma unroll
      for (int i = 0; i < 8; ++i){
        const u64* p = hb + (((c*8 + i)*4 + q)*64 + batch)*2;
        d[2*i]   = H0C ? ld64c(p)     : p[0];
        d[2*i+1] = H0C ? ld64c(p + 1) : p[1];
      }
    };
    int4 xr[8];
    #pragma unroll
    for (int kb = 0; kb < 8; ++kb)            // x part: no dependency
      xr[kb] = xb[(kb*4 + q)*64 + batch];
    #pragma unroll
    for (int kb = 0; kb < 6; ++kb){           // x MMs overlap peers' posting
      bf16x8 b; __builtin_memcpy(&b, &xr[kb], 16); MM(kb, b);
    }
    if (dec) waitL0((unsigned)t);             // own-group join: h0(t-1) ready
    LDH(0, B0); LDH(1, B1); LDH(2, B2);
    { bf16x8 b; __builtin_memcpy(&b, &xr[6], 16); MM(6, b);
                __builtin_memcpy(&b, &xr[7], 16); MM(7, b); }
    CHUNK(8,  B0); LDH(3, B0);
    CHUNK(16, B1);
    CHUNK(24, B2);
    CHUNK(32, B0);
    epilogue(H0, d0, t);
  };

  // ---- layer 1 step: gates = W1 @ [y0(t) ; h1(t-1)] ----
  auto step1 = [&](int t, bool dec){
    a00 = (f32x4){0,0,0,0}; a01 = a00; a10 = a00; a11 = a00;
    const u64* yb = H0 + (size_t)((t+1) % d0)*HSLAB_U64;  // y0(t) slot
    const u64* hb = H1 + (size_t)(t % d1)*HSLAB_U64;      // h1(t-1) slot
    auto LDY = [&](int c, u64* d){
      #pragma unroll
      for (int i = 0; i < 8; ++i){
        const u64* p = yb + (((c*8 + i)*4 + q)*64 + batch)*2;
        d[2*i]   = H0C ? ld64c(p)     : p[0];
        d[2*i+1] = H0C ? ld64c(p + 1) : p[1];
      }
    };
    auto LDH = [&](int c, u64* d){
      #pragma unroll
      for (int i = 0; i < 8; ++i){
        const u64* p = hb + (((c*8 + i)*4 + q)*64 + batch)*2;
        d[2*i]   = H1C ? ld64c(p)     : p[0];
        d[2*i+1] = H1C ? ld64c(p + 1) : p[1];
      }
    };
    if (dec) waitL0((unsigned)(t+1));   // y0(t) ready — instant once L0 ahead
    LDY(0, B0); LDY(1, B1); LDY(2, B2);
    CHUNK(0,  B0); LDY(3, B0);
    CHUNK(8,  B1);
    CHUNK(16, B2);
    if (dec) waitL1((unsigned)t);       // the real join: h1(t-1) ready
    LDH(0, B1); LDH(1, B2);
    CHUNK(24, B0);                      // y chunk 3 hides h1 MALL latency
    LDH(2, B0);
    CHUNK(32, B1);
    LDH(3, B1);
    CHUNK(40, B2);
    CHUNK(48, B0);
    CHUNK(56, B1);
    epilogue(H1, d1, t);
  };

  const bool dec = (d0 >= T_STEPS + 1);  // deep y0 ring => decoupled schedule
  if (!layer){
    if (dec){
      for (int s = 0; s < T_STEPS; ++s){ step0(s, true); postF((unsigned)(s+1)); }
    } else {
      for (int s = 0; s < T_STEPS; ++s){
        step0(s, false); postF((unsigned)(s+1)); waitAll((unsigned)(s+1));
      }
    }
  } else {
    if (dec){
      for (int t = 0; t < T_STEPS; ++t){ step1(t, true); postF((unsigned)(t+1)); }
    } else {
      for (int s = 0; s < T_STEPS; ++s){
        if (s > 0) step1(s-1, false);
        postF((unsigned)(s+1)); waitAll((unsigned)(s+1));
      }
      step1(T_STEPS-1, false);
    }
  }

  // out = [h0 | h1 | c0 | c1], each [B=64, H=1024] fp32
  {
    int col0 = wgl*8 + q;
    int base = layer ? 65536 : 0;
    out[base          + batch*HD + col0    ] = hv[0];
    out[base          + batch*HD + col0 + 4] = hv[1];
    out[base + 131072 + batch*HD + col0    ] = cst[0];
    out[base + 131072 + batch*HD + col0 + 4] = cst[1];
  }
}

extern "C" void kernel_launch(void* const* d_in, const int* in_sizes, int n_in,
                              void* d_out, int out_size, void* d_ws, size_t ws_size,
                              hipStream_t stream)
{
  const float* x    = (const float*)d_in[0];
  const float* Wih0 = (const float*)d_in[1];
  const float* Whh0 = (const float*)d_in[2];
  const float* bih0 = (const float*)d_in[3];
  const float* bhh0 = (const float*)d_in[4];
  const float* Wih1 = (const float*)d_in[5];
  const float* Whh1 = (const float*)d_in[6];
  const float* bih1 = (const float*)d_in[7];
  const float* bhh1 = (const float*)d_in[8];
  float* out = (float*)d_out;

  char* ws = (char*)d_ws;
  unsigned* flags = (unsigned*)ws;
  unsigned* gen   = (unsigned*)(ws + 16384);

  const size_t need2 = FLAGS_BYTES + 2*HIST_BYTES + X8_BYTES;               // ~302 MB
  const size_t need1 = FLAGS_BYTES + HIST_BYTES + 2*HSLAB_BYTES + X8_BYTES; // ~168 MB

  u64 *H0p, *H1p; unsigned short* X8p; int d0, d1, tier;
  if (ws_size >= need2){
    tier = 2; d0 = HIST_DEPTH; d1 = HIST_DEPTH;
    H0p = (u64*)(ws + FLAGS_BYTES);
    H1p = (u64*)(ws + FLAGS_BYTES + HIST_BYTES);
    X8p = (unsigned short*)(ws + FLAGS_BYTES + 2*HIST_BYTES);
  } else if (ws_size >= need1){
    tier = 1; d0 = HIST_DEPTH; d1 = 2;
    H0p = (u64*)(ws + FLAGS_BYTES);
    H1p = (u64*)(ws + FLAGS_BYTES + HIST_BYTES);
    X8p = (unsigned short*)(ws + FLAGS_BYTES + HIST_BYTES + 2*HSLAB_BYTES);
  } else {
    tier = 0; d0 = 2; d1 = 2;
    H0p = (u64*)(ws + FLAGS_BYTES);
    H1p = (u64*)(ws + FLAGS_BYTES + 2*HSLAB_BYTES);
    X8p = (unsigned short*)(ws + FLAGS_BYTES + 4*HSLAB_BYTES);
  }

  // zero flags + slot 0 of each h buffer (initial state h(-1)=0)
  hipMemsetAsync(flags, 0, FLAGS_BYTES, stream);
  hipMemsetAsync(H0p, 0, HSLAB_BYTES, stream);
  hipMemsetAsync(H1p, 0, HSLAB_BYTES, stream);
  xpose_kernel<<<8192, 256, 0, stream>>>(x, X8p);

  void* fn = (tier == 2) ? (void*)&lstm_mega<false,false>
           : (tier == 1) ? (void*)&lstm_mega<false,true>
                         : (void*)&lstm_mega<true,true>;
  hipFuncSetAttribute(fn, hipFuncAttributeMaxDynamicSharedMemorySize, SMEM_BYTES);

  const unsigned short* X8c = X8p;
  void* args[] = {(void*)&Wih0,(void*)&Whh0,(void*)&bih0,(void*)&bhh0,
                  (void*)&Wih1,(void*)&Whh1,(void*)&bih1,(void*)&bhh1,
                  (void*)&X8c,(void*)&flags,(void*)&gen,
                  (void*)&H0p,(void*)&H1p,(void*)&d0,(void*)&d1,(void*)&out};
  hipError_t err = hipLaunchCooperativeKernel(fn, dim3(NWG), dim3(TPB),
                                              args, SMEM_BYTES, stream);
  if (err != hipSuccess){
    // Fallback: plain launch. 256 WGs x 131.6KB LDS => 1 WG/CU, grid == CU
    // count, all WGs co-resident by capacity.
    if (tier == 2)
      lstm_mega<false,false><<<dim3(NWG), dim3(TPB), SMEM_BYTES, stream>>>(
        Wih0,Whh0,bih0,bhh0,Wih1,Whh1,bih1,bhh1,X8c,flags,gen,H0p,H1p,d0,d1,out);
    else if (tier == 1)
      lstm_mega<false,true><<<dim3(NWG), dim3(TPB), SMEM_BYTES, stream>>>(
        Wih0,Whh0,bih0,bhh0,Wih1,Whh1,bih1,bhh1,X8c,flags,gen,H0p,H1p,d0,d1,out);
    else
      lstm_mega<true,true><<<dim3(NWG), dim3(TPB), SMEM_BYTES, stream>>>(
        Wih0,Whh0,bih0,bhh0,Wih1,Whh1,bih1,bhh1,X8c,flags,gen,H0p,H1p,d0,d1,out);
  }
}